// Round 1
// baseline (143.036 us; speedup 1.0000x reference)
//
#include <hip/hip_runtime.h>

#define EPS 1e-6f
#define TILE 256

static __device__ __forceinline__ float wave_reduce_add(float v) {
#pragma unroll
    for (int o = 32; o > 0; o >>= 1) v += __shfl_down(v, o, 64);
    return v;
}

// ws float layout per batch (stride 8):
// 0 cn_num 1 cn_den 2 cacn_num 3 cacn_den 4 cnca_num 5 cnca_den 6 clash_sum 7 within_sum
__global__ void init_ws_kernel(float* ws, int n) {
    int i = blockIdx.x * blockDim.x + threadIdx.x;
    if (i < n) ws[i] = 0.f;
}

__global__ void bonds_kernel(const float* __restrict__ pos, const float* __restrict__ am,
                             const int* __restrict__ rtypes, const int* __restrict__ rindex,
                             float* __restrict__ ws, int N) {
    int b = blockIdx.x;
    const float* P = pos + (size_t)b * N * 42;
    const float* M = am + (size_t)b * N * 14;
    const int* RT = rtypes + (size_t)b * N;
    const int* RI = rindex + (size_t)b * N;
    float n0 = 0.f, de0 = 0.f, n1 = 0.f, de1 = 0.f, n2 = 0.f, de2 = 0.f;
    for (int i = threadIdx.x; i < N - 1; i += blockDim.x) {
        float no_gap = (RI[i + 1] - RI[i] == 1) ? 1.f : 0.f;
        const float* ca0 = P + i * 42 + 3;        // this CA (slot 1)
        const float* c0  = P + i * 42 + 6;        // this C  (slot 2)
        const float* nn  = P + (i + 1) * 42 + 0;  // next N  (slot 0)
        const float* ca1 = P + (i + 1) * 42 + 3;  // next CA (slot 1)
        float m_ca0 = M[i * 14 + 1], m_c0 = M[i * 14 + 2];
        float m_nn = M[(i + 1) * 14 + 0], m_ca1 = M[(i + 1) * 14 + 1];

        // C-N bond length
        float bx = nn[0] - c0[0], by = nn[1] - c0[1], bz = nn[2] - c0[2];
        float c_n_len = sqrtf(bx * bx + by * by + bz * bz + EPS);
        float pro = (RT[i + 1] == 14) ? 1.f : 0.f;
        float gt_len = (1.f - pro) * 1.329f + pro * 1.341f;
        float gt_std = (1.f - pro) * 0.014f + pro * 0.016f;
        float cnm = m_c0 * m_nn * no_gap;
        float dl = c_n_len - gt_len;
        float cne = sqrtf(dl * dl + EPS);
        n0 += cnm * fmaxf(cne - 12.f * gt_std, 0.f);
        de0 += cnm;

        // unit vectors
        float ax = ca0[0] - c0[0], ay = ca0[1] - c0[1], az = ca0[2] - c0[2];
        float ca_c_len = sqrtf(ax * ax + ay * ay + az * az + EPS);
        float ex = ca1[0] - nn[0], ey = ca1[1] - nn[1], ez = ca1[2] - nn[2];
        float n_ca_len = sqrtf(ex * ex + ey * ey + ez * ez + EPS);
        float inv_cn = 1.f / c_n_len, inv_ac = 1.f / ca_c_len, inv_nc = 1.f / n_ca_len;
        float ux = bx * inv_cn, uy = by * inv_cn, uz = bz * inv_cn;       // c_n_u
        float cx = ax * inv_ac, cy = ay * inv_ac, cz = az * inv_ac;       // c_ca_u
        float wx = ex * inv_nc, wy = ey * inv_nc, wz = ez * inv_nc;       // n_ca_u

        // CA-C-N angle
        float cacn = cx * ux + cy * uy + cz * uz;
        float m1 = m_ca0 * m_c0 * m_nn * no_gap;
        float t1 = cacn + 0.5203f;
        float e1 = sqrtf(t1 * t1 + EPS);
        n1 += m1 * fmaxf(e1 - 12.f * 0.0353f, 0.f);
        de1 += m1;

        // C-N-CA angle
        float cnca = -(ux * wx + uy * wy + uz * wz);
        float m2 = m_c0 * m_nn * m_ca1 * no_gap;
        float t2 = cnca + 0.4473f;
        float e2 = sqrtf(t2 * t2 + EPS);
        n2 += m2 * fmaxf(e2 - 12.f * 0.0311f, 0.f);
        de2 += m2;
    }
    n0 = wave_reduce_add(n0); de0 = wave_reduce_add(de0);
    n1 = wave_reduce_add(n1); de1 = wave_reduce_add(de1);
    n2 = wave_reduce_add(n2); de2 = wave_reduce_add(de2);
    if ((threadIdx.x & 63) == 0) {
        float* W = ws + b * 8;
        atomicAdd(&W[0], n0); atomicAdd(&W[1], de0);
        atomicAdd(&W[2], n1); atomicAdd(&W[3], de1);
        atomicAdd(&W[4], n2); atomicAdd(&W[5], de2);
    }
}

__global__ void within_kernel(const float* __restrict__ pos, const float* __restrict__ am,
                              const int* __restrict__ rtypes,
                              const float* __restrict__ lbt, const float* __restrict__ ubt,
                              float* __restrict__ ws, int N) {
    int b = blockIdx.y;
    int total = N * 196;
    float sum = 0.f;
    for (int idx = blockIdx.x * blockDim.x + threadIdx.x; idx < total;
         idx += gridDim.x * blockDim.x) {
        int n = idx / 196;
        int p = idx - n * 196;
        int i = p / 14;
        int j = p - i * 14;
        if (i == j) continue;
        size_t bn = (size_t)b * N + n;
        int rt = rtypes[bn]; rt = rt < 20 ? rt : 20;
        const float* pi = pos + bn * 42 + i * 3;
        const float* pj = pos + bn * 42 + j * 3;
        float dx = pi[0] - pj[0], dy = pi[1] - pj[1], dz = pi[2] - pj[2];
        float d = sqrtf(dx * dx + dy * dy + dz * dz + 1e-8f);
        float lb = lbt[rt * 196 + p], ub = ubt[rt * 196 + p];
        float gate = (lb > 0.f || ub > 0.f) ? 1.f : 0.f;
        float m = am[bn * 14 + i] * am[bn * 14 + j] * gate;
        sum += (fmaxf(lb - d, 0.f) + fmaxf(d - ub, 0.f)) * m;
    }
    sum = wave_reduce_add(sum);
    if ((threadIdx.x & 63) == 0 && sum != 0.f) atomicAdd(&ws[b * 8 + 7], sum);
}

__global__ void clash_kernel(const float* __restrict__ pos, const float* __restrict__ am,
                             const int* __restrict__ rtypes, const int* __restrict__ rindex,
                             const float* __restrict__ vdw, float* __restrict__ ws, int N) {
    const int INTMAX = 0x7fffffff;
    const int INTMIN = (int)0x80000000;
    int b = blockIdx.z;
    int A = N * 14;
    const float* P = pos + (size_t)b * A * 3;
    const float* M = am + (size_t)b * A;
    const int* RT = rtypes + (size_t)b * N;
    const int* RI = rindex + (size_t)b * N;

    __shared__ float4 sP[TILE];
    __shared__ float sM[TILE];
    __shared__ int sRI[TILE];
    __shared__ int sRT[TILE];
    __shared__ int sSL[TILE];
    __shared__ int redI[4], redJ[4];
    __shared__ int skip_flag;

    int t = threadIdx.x;
    int j = blockIdx.y * TILE + t;
    int jri = INTMIN;
    if (j < A) {
        int res = j / 14;
        int sl = j - res * 14;
        int rt = RT[res];
        int rtc = rt < 20 ? rt : 20;
        sP[t] = make_float4(P[j * 3], P[j * 3 + 1], P[j * 3 + 2], vdw[rtc * 14 + sl]);
        sM[t] = M[j];
        jri = RI[res];
        sRI[t] = jri; sRT[t] = rt; sSL[t] = sl;
    } else {
        sP[t] = make_float4(1e30f, 1e30f, 1e30f, 0.f);
        sM[t] = 0.f; sRI[t] = INTMIN; sRT[t] = -1; sSL[t] = -1;
    }

    int i = blockIdx.x * TILE + t;
    float xi = 0.f, yi = 0.f, zi = 0.f, vi = 0.f, mi = 0.f;
    int iri = INTMAX, irt = -1, isl = -1;
    if (i < A) {
        int res = i / 14;
        isl = i - res * 14;
        irt = RT[res];
        int rtc = irt < 20 ? irt : 20;
        vi = vdw[rtc * 14 + isl];
        xi = P[i * 3]; yi = P[i * 3 + 1]; zi = P[i * 3 + 2];
        mi = M[i];
        iri = RI[res];
    }

    // block-exact early exit: pairs need iri < jri
    int wmin = iri, wmax = jri;
#pragma unroll
    for (int o = 32; o > 0; o >>= 1) {
        wmin = min(wmin, __shfl_down(wmin, o, 64));
        wmax = max(wmax, __shfl_down(wmax, o, 64));
    }
    int lane = t & 63, wid = t >> 6;
    if (lane == 0) { redI[wid] = wmin; redJ[wid] = wmax; }
    __syncthreads();
    if (t == 0) {
        int mn = min(min(redI[0], redI[1]), min(redI[2], redI[3]));
        int mx = max(max(redJ[0], redJ[1]), max(redJ[2], redJ[3]));
        skip_flag = (mn >= mx) ? 1 : 0;
    }
    __syncthreads();
    if (skip_flag) return;

    float sum = 0.f;
    if (i < A && mi != 0.f) {
        float vis = vi - 1.5f;  // CLASH_TOL
#pragma unroll 4
        for (int jj = 0; jj < TILE; ++jj) {
            float4 pj = sP[jj];
            float dx = xi - pj.x, dy = yi - pj.y, dz = zi - pj.z;
            float d2 = dx * dx + dy * dy + dz * dz + 1e-8f;
            float s = vis + pj.w;
            if (d2 < s * s && s > 0.f) {
                int jri2 = sRI[jj];
                if (iri < jri2) {
                    int dj = jri2 - iri;
                    // C-N peptide bond: (slot_i==2 && slot_j==0 && dj==1); the mirrored
                    // branch needs dj==-1 which contradicts iri<jri2.
                    bool cn = (isl == 2 && sSL[jj] == 0 && dj == 1);
                    bool ssb = (irt == 4 && sRT[jj] == 4 && isl == 5 && sSL[jj] == 5);
                    if (!cn && !ssb) {
                        float dist = sqrtf(d2);
                        sum += (s - dist) * mi * sM[jj];
                    }
                }
            }
        }
    }
    sum = wave_reduce_add(sum);
    if (lane == 0 && sum != 0.f) atomicAdd(&ws[b * 8 + 6], sum);
}

__global__ void final_kernel(const float* __restrict__ am, const float* __restrict__ ws,
                             float* __restrict__ out, int N) {
    int b = blockIdx.x;
    const float* M = am + (size_t)b * N * 14;
    float s = 0.f;
    for (int i = threadIdx.x; i < N * 14; i += blockDim.x) s += M[i];
    s = wave_reduce_add(s);
    __shared__ float red[4];
    int lane = threadIdx.x & 63, wid = threadIdx.x >> 6;
    if (lane == 0) red[wid] = s;
    __syncthreads();
    if (threadIdx.x == 0) {
        float na = red[0] + red[1] + red[2] + red[3];
        na = fmaxf(na, 1e-6f);
        const float* W = ws + b * 8;
        float loss = W[0] / (W[1] + EPS) + W[2] / (W[3] + EPS) + W[4] / (W[5] + EPS)
                   + 2.f * (W[6] + W[7]) / na;
        out[b] = loss;
    }
}

extern "C" void kernel_launch(void* const* d_in, const int* in_sizes, int n_in,
                              void* d_out, int out_size, void* d_ws, size_t ws_size,
                              hipStream_t stream) {
    const float* pos = (const float*)d_in[0];
    const float* am = (const float*)d_in[1];
    const int* rtypes = (const int*)d_in[2];
    const int* rindex = (const int*)d_in[3];
    const float* vdw = (const float*)d_in[4];
    const float* lbt = (const float*)d_in[5];
    const float* ubt = (const float*)d_in[6];
    float* out = (float*)d_out;
    float* ws = (float*)d_ws;

    int B = out_size;               // output shape (B,)
    int N = in_sizes[2] / B;        // residue_types is (B, N)
    int A = N * 14;

    init_ws_kernel<<<1, 64, 0, stream>>>(ws, 8 * B);
    bonds_kernel<<<B, 256, 0, stream>>>(pos, am, rtypes, rindex, ws, N);
    dim3 wgrid((N * 196 + 255) / 256, B);
    within_kernel<<<wgrid, 256, 0, stream>>>(pos, am, rtypes, lbt, ubt, ws, N);
    int tiles = (A + TILE - 1) / TILE;
    dim3 cgrid(tiles, tiles, B);
    clash_kernel<<<cgrid, 256, 0, stream>>>(pos, am, rtypes, rindex, vdw, ws, N);
    final_kernel<<<B, 256, 0, stream>>>(am, ws, out, N);
}

// Round 2
// 105.964 us; speedup vs baseline: 1.3499x; 1.3499x over previous
//
#include <hip/hip_runtime.h>

#define EPS 1e-6f
#define JT 128           // tile size (both i and j)
#define WB 64            // within-residue blocks

static __device__ __forceinline__ float wave_reduce_add(float v) {
#pragma unroll
    for (int o = 32; o > 0; o >>= 1) v += __shfl_down(v, o, 64);
    return v;
}

// ws float layout per batch (stride 8):
// 0 cn_num 1 cn_den 2 cacn_num 3 cacn_den 4 cnca_num 5 cnca_den 6 clash_sum 7 within_sum

__device__ void do_bonds(const float* __restrict__ P, const float* __restrict__ M,
                         const int* __restrict__ RT, const int* __restrict__ RI,
                         float* __restrict__ W, int N) {
    float n0 = 0.f, de0 = 0.f, n1 = 0.f, de1 = 0.f, n2 = 0.f, de2 = 0.f;
    for (int i = threadIdx.x; i < N - 1; i += blockDim.x) {
        float no_gap = (RI[i + 1] - RI[i] == 1) ? 1.f : 0.f;
        const float* ca0 = P + i * 42 + 3;
        const float* c0  = P + i * 42 + 6;
        const float* nn  = P + (i + 1) * 42 + 0;
        const float* ca1 = P + (i + 1) * 42 + 3;
        float m_ca0 = M[i * 14 + 1], m_c0 = M[i * 14 + 2];
        float m_nn = M[(i + 1) * 14 + 0], m_ca1 = M[(i + 1) * 14 + 1];

        float bx = nn[0] - c0[0], by = nn[1] - c0[1], bz = nn[2] - c0[2];
        float c_n_len = sqrtf(bx * bx + by * by + bz * bz + EPS);
        float pro = (RT[i + 1] == 14) ? 1.f : 0.f;
        float gt_len = (1.f - pro) * 1.329f + pro * 1.341f;
        float gt_std = (1.f - pro) * 0.014f + pro * 0.016f;
        float cnm = m_c0 * m_nn * no_gap;
        float dl = c_n_len - gt_len;
        float cne = sqrtf(dl * dl + EPS);
        n0 += cnm * fmaxf(cne - 12.f * gt_std, 0.f);
        de0 += cnm;

        float ax = ca0[0] - c0[0], ay = ca0[1] - c0[1], az = ca0[2] - c0[2];
        float ca_c_len = sqrtf(ax * ax + ay * ay + az * az + EPS);
        float ex = ca1[0] - nn[0], ey = ca1[1] - nn[1], ez = ca1[2] - nn[2];
        float n_ca_len = sqrtf(ex * ex + ey * ey + ez * ez + EPS);
        float inv_cn = 1.f / c_n_len, inv_ac = 1.f / ca_c_len, inv_nc = 1.f / n_ca_len;
        float ux = bx * inv_cn, uy = by * inv_cn, uz = bz * inv_cn;
        float cx = ax * inv_ac, cy = ay * inv_ac, cz = az * inv_ac;
        float wx = ex * inv_nc, wy = ey * inv_nc, wz = ez * inv_nc;

        float cacn = cx * ux + cy * uy + cz * uz;
        float m1 = m_ca0 * m_c0 * m_nn * no_gap;
        float t1 = cacn + 0.5203f;
        float e1 = sqrtf(t1 * t1 + EPS);
        n1 += m1 * fmaxf(e1 - 12.f * 0.0353f, 0.f);
        de1 += m1;

        float cnca = -(ux * wx + uy * wy + uz * wz);
        float m2 = m_c0 * m_nn * m_ca1 * no_gap;
        float t2 = cnca + 0.4473f;
        float e2 = sqrtf(t2 * t2 + EPS);
        n2 += m2 * fmaxf(e2 - 12.f * 0.0311f, 0.f);
        de2 += m2;
    }
    n0 = wave_reduce_add(n0); de0 = wave_reduce_add(de0);
    n1 = wave_reduce_add(n1); de1 = wave_reduce_add(de1);
    n2 = wave_reduce_add(n2); de2 = wave_reduce_add(de2);
    __shared__ float red[12];
    int lane = threadIdx.x & 63, wid = threadIdx.x >> 6;
    if (lane == 0) {
        red[wid * 6 + 0] = n0; red[wid * 6 + 1] = de0; red[wid * 6 + 2] = n1;
        red[wid * 6 + 3] = de1; red[wid * 6 + 4] = n2; red[wid * 6 + 5] = de2;
    }
    __syncthreads();
    if (threadIdx.x == 0) {
        atomicAdd(&W[0], red[0] + red[6]); atomicAdd(&W[1], red[1] + red[7]);
        atomicAdd(&W[2], red[2] + red[8]); atomicAdd(&W[3], red[3] + red[9]);
        atomicAdd(&W[4], red[4] + red[10]); atomicAdd(&W[5], red[5] + red[11]);
    }
}

__device__ void do_within(const float* __restrict__ pos, const float* __restrict__ am,
                          const int* __restrict__ rtypes,
                          const float* __restrict__ lbt, const float* __restrict__ ubt,
                          float* __restrict__ W, int N, int b, int wblk) {
    int total = N * 196;
    float sum = 0.f;
    for (int idx = wblk * blockDim.x + threadIdx.x; idx < total; idx += WB * blockDim.x) {
        int n = idx / 196;
        int p = idx - n * 196;
        int i = p / 14;
        int j = p - i * 14;
        if (i == j) continue;
        size_t bn = (size_t)b * N + n;
        int rt = rtypes[bn]; rt = rt < 20 ? rt : 20;
        const float* pi = pos + bn * 42 + i * 3;
        const float* pj = pos + bn * 42 + j * 3;
        float dx = pi[0] - pj[0], dy = pi[1] - pj[1], dz = pi[2] - pj[2];
        float d = sqrtf(dx * dx + dy * dy + dz * dz + 1e-8f);
        float lb = lbt[rt * 196 + p], ub = ubt[rt * 196 + p];
        float gate = (lb > 0.f || ub > 0.f) ? 1.f : 0.f;
        float m = am[bn * 14 + i] * am[bn * 14 + j] * gate;
        sum += (fmaxf(lb - d, 0.f) + fmaxf(d - ub, 0.f)) * m;
    }
    sum = wave_reduce_add(sum);
    __shared__ float red2[2];
    int lane = threadIdx.x & 63, wid = threadIdx.x >> 6;
    if (lane == 0) red2[wid] = sum;
    __syncthreads();
    if (threadIdx.x == 0) {
        float s = red2[0] + red2[1];
        if (s != 0.f) atomicAdd(&W[7], s);
    }
}

__device__ void do_clash(const float* __restrict__ P, const float* __restrict__ M,
                         const int* __restrict__ RT, const int* __restrict__ RI,
                         const float* __restrict__ vdw, float* __restrict__ W,
                         int N, int A, int T, int p) {
    // invert triangular index p -> (bi, bj), bi <= bj, row-major upper triangle
    int bi = (int)floorf(((float)(2 * T + 1)
                - sqrtf((float)((2 * T + 1) * (2 * T + 1) - 8 * p))) * 0.5f);
    bi = bi < 0 ? 0 : (bi >= T ? T - 1 : bi);
    // start(r) = r*T - r*(r-1)/2
    while (bi + 1 <= T - 1 && ((bi + 1) * T - (bi + 1) * bi / 2) <= p) ++bi;
    while ((bi * T - bi * (bi - 1) / 2) > p) --bi;
    int bj = bi + (p - (bi * T - bi * (bi - 1) / 2));

    __shared__ float4 sPos[JT];   // x,y,z,vdw
    __shared__ float sMask[JT];
    __shared__ int sRI[JT];
    __shared__ int sMeta[JT];     // slot | (cys5<<4)

    int t = threadIdx.x;
    int j = bj * JT + t;
    if (j < A) {
        int res = j / 14;
        int sl = j - res * 14;
        int rt = RT[res];
        int rtc = rt < 20 ? rt : 20;
        sPos[t] = make_float4(P[j * 3], P[j * 3 + 1], P[j * 3 + 2], vdw[rtc * 14 + sl]);
        sMask[t] = M[j];
        sRI[t] = RI[res];
        sMeta[t] = sl | (((rt == 4) && (sl == 5)) ? 16 : 0);
    } else {
        sPos[t] = make_float4(1e30f, 1e30f, 1e30f, -1e30f);
        sMask[t] = 0.f; sRI[t] = 0x7fffffff; sMeta[t] = 0;
    }
    __syncthreads();

    int i = bi * JT + t;
    float sum = 0.f;
    if (i < A) {
        int res = i / 14;
        int isl = i - res * 14;
        int irt = RT[res];
        int rtc = irt < 20 ? irt : 20;
        float vis = vdw[rtc * 14 + isl] - 1.5f;   // vdw_i - CLASH_TOL
        float xi = P[i * 3], yi = P[i * 3 + 1], zi = P[i * 3 + 2];
        float mi = M[i];
        int iri = RI[res];
        bool icys = (irt == 4) && (isl == 5);
        if (mi != 0.f) {
            for (int base = 0; base < JT; base += 8) {
                float4 r[8];
#pragma unroll
                for (int k = 0; k < 8; ++k) r[k] = sPos[base + k];
#pragma unroll
                for (int k = 0; k < 8; ++k) {
                    float dx = xi - r[k].x, dy = yi - r[k].y, dz = zi - r[k].z;
                    float d2 = dx * dx + dy * dy + dz * dz + 1e-8f;
                    float s = vis + r[k].w;
                    if (d2 < s * s && s > 0.f) {
                        int jj = base + k;
                        int jg = bj * JT + jj;
                        if (i < jg) {
                            int jri = sRI[jj];
                            if (iri != jri) {
                                int dj = jri - iri;
                                int jmeta = sMeta[jj];
                                int jsl = jmeta & 15;
                                bool cn = (isl == 2 && jsl == 0 && dj == 1) ||
                                          (isl == 0 && jsl == 2 && dj == -1);
                                bool ssb = icys && (jmeta & 16);
                                if (!cn && !ssb) {
                                    sum += (s - sqrtf(d2)) * mi * sMask[jj];
                                }
                            }
                        }
                    }
                }
            }
        }
    }
    sum = wave_reduce_add(sum);
    __shared__ float red3[2];
    int lane = t & 63, wid = t >> 6;
    if (lane == 0) red3[wid] = sum;
    __syncthreads();
    if (t == 0) {
        float s = red3[0] + red3[1];
        if (s != 0.f) atomicAdd(&W[6], s);
    }
}

__global__ __launch_bounds__(JT) void main_kernel(
        const float* __restrict__ pos, const float* __restrict__ am,
        const int* __restrict__ rtypes, const int* __restrict__ rindex,
        const float* __restrict__ vdw, const float* __restrict__ lbt,
        const float* __restrict__ ubt, float* __restrict__ ws,
        int N, int A, int T, int CB) {
    int b = blockIdx.y;
    const float* P = pos + (size_t)b * A * 3;
    const float* M = am + (size_t)b * A;
    const int* RT = rtypes + (size_t)b * N;
    const int* RI = rindex + (size_t)b * N;
    float* W = ws + b * 8;
    int bid = blockIdx.x;
    if (bid < CB) {
        do_clash(P, M, RT, RI, vdw, W, N, A, T, bid);
    } else if (bid < CB + WB) {
        do_within(pos, am, rtypes, lbt, ubt, W, N, b, bid - CB);
    } else {
        do_bonds(P, M, RT, RI, W, N);
    }
}

__global__ __launch_bounds__(128) void final_kernel(
        const float* __restrict__ am, const float* __restrict__ ws,
        float* __restrict__ out, int N) {
    int b = blockIdx.x;
    const float* M = am + (size_t)b * N * 14;
    float s = 0.f;
    for (int i = threadIdx.x; i < N * 14; i += blockDim.x) s += M[i];
    s = wave_reduce_add(s);
    __shared__ float red[2];
    int lane = threadIdx.x & 63, wid = threadIdx.x >> 6;
    if (lane == 0) red[wid] = s;
    __syncthreads();
    if (threadIdx.x == 0) {
        float na = fmaxf(red[0] + red[1], 1e-6f);
        const float* W = ws + b * 8;
        float loss = W[0] / (W[1] + EPS) + W[2] / (W[3] + EPS) + W[4] / (W[5] + EPS)
                   + 2.f * (W[6] + W[7]) / na;
        out[b] = loss;
    }
}

extern "C" void kernel_launch(void* const* d_in, const int* in_sizes, int n_in,
                              void* d_out, int out_size, void* d_ws, size_t ws_size,
                              hipStream_t stream) {
    const float* pos = (const float*)d_in[0];
    const float* am = (const float*)d_in[1];
    const int* rtypes = (const int*)d_in[2];
    const int* rindex = (const int*)d_in[3];
    const float* vdw = (const float*)d_in[4];
    const float* lbt = (const float*)d_in[5];
    const float* ubt = (const float*)d_in[6];
    float* out = (float*)d_out;
    float* ws = (float*)d_ws;

    int B = out_size;
    int N = in_sizes[2] / B;
    int A = N * 14;
    int T = (A + JT - 1) / JT;
    int CB = T * (T + 1) / 2;

    hipMemsetAsync(ws, 0, (size_t)B * 8 * sizeof(float), stream);
    dim3 grid(CB + WB + 1, B);
    main_kernel<<<grid, JT, 0, stream>>>(pos, am, rtypes, rindex, vdw, lbt, ubt,
                                         ws, N, A, T, CB);
    final_kernel<<<B, 128, 0, stream>>>(am, ws, out, N);
}

// Round 4
// 101.891 us; speedup vs baseline: 1.4038x; 1.0400x over previous
//
#include <hip/hip_runtime.h>

#define EPS 1e-6f
#define JT 256           // clash tile size = block size
#define WB 56            // within-residue blocks

static __device__ __forceinline__ float wave_reduce_add(float v) {
#pragma unroll
    for (int o = 32; o > 0; o >>= 1) v += __shfl_down(v, o, 64);
    return v;
}

// ws layout per batch (stride = NBP + 6 floats):
//   [0, NBP)        per-block pair-loss partials (clash blocks + within blocks)
//   [NBP, NBP+6)    bonds: cn_num cn_den cacn_num cacn_den cnca_num cnca_den
// Every slot is written unconditionally every launch -> no zero-init needed.

__device__ void do_bonds(const float* __restrict__ P, const float* __restrict__ M,
                         const int* __restrict__ RT, const int* __restrict__ RI,
                         float* __restrict__ Wtail, int N) {
    float n0 = 0.f, de0 = 0.f, n1 = 0.f, de1 = 0.f, n2 = 0.f, de2 = 0.f;
    for (int i = threadIdx.x; i < N - 1; i += blockDim.x) {
        float no_gap = (RI[i + 1] - RI[i] == 1) ? 1.f : 0.f;
        const float* ca0 = P + i * 42 + 3;
        const float* c0  = P + i * 42 + 6;
        const float* nn  = P + (i + 1) * 42 + 0;
        const float* ca1 = P + (i + 1) * 42 + 3;
        float m_ca0 = M[i * 14 + 1], m_c0 = M[i * 14 + 2];
        float m_nn = M[(i + 1) * 14 + 0], m_ca1 = M[(i + 1) * 14 + 1];

        float bx = nn[0] - c0[0], by = nn[1] - c0[1], bz = nn[2] - c0[2];
        float c_n_len = sqrtf(bx * bx + by * by + bz * bz + EPS);
        float pro = (RT[i + 1] == 14) ? 1.f : 0.f;
        float gt_len = (1.f - pro) * 1.329f + pro * 1.341f;
        float gt_std = (1.f - pro) * 0.014f + pro * 0.016f;
        float cnm = m_c0 * m_nn * no_gap;
        float dl = c_n_len - gt_len;
        float cne = sqrtf(dl * dl + EPS);
        n0 += cnm * fmaxf(cne - 12.f * gt_std, 0.f);
        de0 += cnm;

        float ax = ca0[0] - c0[0], ay = ca0[1] - c0[1], az = ca0[2] - c0[2];
        float ca_c_len = sqrtf(ax * ax + ay * ay + az * az + EPS);
        float ex = ca1[0] - nn[0], ey = ca1[1] - nn[1], ez = ca1[2] - nn[2];
        float n_ca_len = sqrtf(ex * ex + ey * ey + ez * ez + EPS);
        float inv_cn = 1.f / c_n_len, inv_ac = 1.f / ca_c_len, inv_nc = 1.f / n_ca_len;
        float ux = bx * inv_cn, uy = by * inv_cn, uz = bz * inv_cn;
        float cx = ax * inv_ac, cy = ay * inv_ac, cz = az * inv_ac;
        float wx = ex * inv_nc, wy = ey * inv_nc, wz = ez * inv_nc;

        float cacn = cx * ux + cy * uy + cz * uz;
        float m1 = m_ca0 * m_c0 * m_nn * no_gap;
        float t1 = cacn + 0.5203f;
        float e1 = sqrtf(t1 * t1 + EPS);
        n1 += m1 * fmaxf(e1 - 12.f * 0.0353f, 0.f);
        de1 += m1;

        float cnca = -(ux * wx + uy * wy + uz * wz);
        float m2 = m_c0 * m_nn * m_ca1 * no_gap;
        float t2 = cnca + 0.4473f;
        float e2 = sqrtf(t2 * t2 + EPS);
        n2 += m2 * fmaxf(e2 - 12.f * 0.0311f, 0.f);
        de2 += m2;
    }
    n0 = wave_reduce_add(n0); de0 = wave_reduce_add(de0);
    n1 = wave_reduce_add(n1); de1 = wave_reduce_add(de1);
    n2 = wave_reduce_add(n2); de2 = wave_reduce_add(de2);
    __shared__ float red[24];
    int lane = threadIdx.x & 63, wid = threadIdx.x >> 6;
    if (lane == 0) {
        red[wid * 6 + 0] = n0; red[wid * 6 + 1] = de0; red[wid * 6 + 2] = n1;
        red[wid * 6 + 3] = de1; red[wid * 6 + 4] = n2; red[wid * 6 + 5] = de2;
    }
    __syncthreads();
    if (threadIdx.x < 6) {
        Wtail[threadIdx.x] = red[threadIdx.x] + red[6 + threadIdx.x]
                           + red[12 + threadIdx.x] + red[18 + threadIdx.x];
    }
}

__device__ void do_within(const float* __restrict__ pos, const float* __restrict__ am,
                          const int* __restrict__ rtypes,
                          const float* __restrict__ lbt, const float* __restrict__ ubt,
                          float* __restrict__ slot, int N, int b, int wblk) {
    int total = N * 196;
    float sum = 0.f;
    for (int idx = wblk * blockDim.x + threadIdx.x; idx < total; idx += WB * blockDim.x) {
        int n = idx / 196;
        int p = idx - n * 196;
        int i = p / 14;
        int j = p - i * 14;
        if (i == j) continue;
        size_t bn = (size_t)b * N + n;
        int rt = rtypes[bn]; rt = rt < 20 ? rt : 20;
        const float* pi = pos + bn * 42 + i * 3;
        const float* pj = pos + bn * 42 + j * 3;
        float dx = pi[0] - pj[0], dy = pi[1] - pj[1], dz = pi[2] - pj[2];
        float d = sqrtf(dx * dx + dy * dy + dz * dz + 1e-8f);
        float lb = lbt[rt * 196 + p], ub = ubt[rt * 196 + p];
        float gate = (lb > 0.f || ub > 0.f) ? 1.f : 0.f;
        float m = am[bn * 14 + i] * am[bn * 14 + j] * gate;
        sum += (fmaxf(lb - d, 0.f) + fmaxf(d - ub, 0.f)) * m;
    }
    sum = wave_reduce_add(sum);
    __shared__ float red2[4];
    int lane = threadIdx.x & 63, wid = threadIdx.x >> 6;
    if (lane == 0) red2[wid] = sum;
    __syncthreads();
    if (threadIdx.x == 0) *slot = red2[0] + red2[1] + red2[2] + red2[3];
}

__device__ void do_clash(const float* __restrict__ P, const float* __restrict__ M,
                         const int* __restrict__ RT, const int* __restrict__ RI,
                         const float* __restrict__ vdw, float* __restrict__ slot,
                         int N, int A, int T, int p) {
    // invert triangular index p -> (bi, bj), bi <= bj; start(r) = r*T - r*(r-1)/2
    int bi = (int)floorf(((float)(2 * T + 1)
                - sqrtf((float)((2 * T + 1) * (2 * T + 1) - 8 * p))) * 0.5f);
    bi = bi < 0 ? 0 : (bi >= T ? T - 1 : bi);
    while (bi + 1 <= T - 1 && ((bi + 1) * T - (bi + 1) * bi / 2) <= p) ++bi;
    while ((bi * T - bi * (bi - 1) / 2) > p) --bi;
    int bj = bi + (p - (bi * T - bi * (bi - 1) / 2));

    __shared__ float4 sPos[JT];   // x,y,z,vdw
    __shared__ float sMask[JT];
    __shared__ int sRI[JT];
    __shared__ int sMeta[JT];     // slot | (cys-SG << 4)

    int t = threadIdx.x;
    int j = bj * JT + t;
    if (j < A) {
        int res = j / 14;
        int sl = j - res * 14;
        int rt = RT[res];
        int rtc = rt < 20 ? rt : 20;
        sPos[t] = make_float4(P[j * 3], P[j * 3 + 1], P[j * 3 + 2], vdw[rtc * 14 + sl]);
        sMask[t] = M[j];
        sRI[t] = RI[res];
        sMeta[t] = sl | (((rt == 4) && (sl == 5)) ? 16 : 0);
    } else {
        sPos[t] = make_float4(1e30f, 1e30f, 1e30f, -1e30f);
        sMask[t] = 0.f; sRI[t] = 0x7fffffff; sMeta[t] = 0;
    }
    __syncthreads();

    int i = bi * JT + t;
    float sum = 0.f;
    if (i < A) {
        int res = i / 14;
        int isl = i - res * 14;
        int irt = RT[res];
        int rtc = irt < 20 ? irt : 20;
        float vis = vdw[rtc * 14 + isl] - 1.5f;   // vdw_i - CLASH_TOL
        float xi = P[i * 3], yi = P[i * 3 + 1], zi = P[i * 3 + 2];
        float mi = M[i];
        int iri = RI[res];
        bool icys = (irt == 4) && (isl == 5);
        if (mi != 0.f) {
            for (int base = 0; base < JT; base += 8) {
                float4 r[8];
#pragma unroll
                for (int k = 0; k < 8; ++k) r[k] = sPos[base + k];
#pragma unroll
                for (int k = 0; k < 8; ++k) {
                    float dx = xi - r[k].x, dy = yi - r[k].y, dz = zi - r[k].z;
                    float d2 = dx * dx + dy * dy + dz * dz + 1e-8f;
                    float s = vis + r[k].w;
                    if (d2 < s * s && s > 0.f) {
                        int jj = base + k;
                        int jg = bj * JT + jj;
                        if (i < jg) {
                            int jri = sRI[jj];
                            if (iri != jri) {
                                int dj = jri - iri;
                                int jmeta = sMeta[jj];
                                int jsl = jmeta & 15;
                                bool cn = (isl == 2 && jsl == 0 && dj == 1) ||
                                          (isl == 0 && jsl == 2 && dj == -1);
                                bool ssb = icys && (jmeta & 16);
                                if (!cn && !ssb) {
                                    sum += (s - sqrtf(d2)) * mi * sMask[jj];
                                }
                            }
                        }
                    }
                }
            }
        }
    }
    sum = wave_reduce_add(sum);
    __shared__ float red3[4];
    int lane = t & 63, wid = t >> 6;
    if (lane == 0) red3[wid] = sum;
    __syncthreads();
    if (t == 0) *slot = red3[0] + red3[1] + red3[2] + red3[3];
}

__global__ __launch_bounds__(JT) void main_kernel(
        const float* __restrict__ pos, const float* __restrict__ am,
        const int* __restrict__ rtypes, const int* __restrict__ rindex,
        const float* __restrict__ vdw, const float* __restrict__ lbt,
        const float* __restrict__ ubt, float* __restrict__ ws,
        int N, int A, int T, int CB, int NBP, int stride) {
    int b = blockIdx.y;
    const float* P = pos + (size_t)b * A * 3;
    const float* M = am + (size_t)b * A;
    const int* RT = rtypes + (size_t)b * N;
    const int* RI = rindex + (size_t)b * N;
    float* W = ws + (size_t)b * stride;
    int bid = blockIdx.x;
    if (bid < CB) {
        do_clash(P, M, RT, RI, vdw, &W[bid], N, A, T, bid);
    } else if (bid < NBP) {
        do_within(pos, am, rtypes, lbt, ubt, &W[bid], N, b, bid - CB);
    } else {
        do_bonds(P, M, RT, RI, &W[NBP], N);
    }
}

__global__ __launch_bounds__(256) void final_kernel(
        const float* __restrict__ am, const float* __restrict__ ws,
        float* __restrict__ out, int N, int NBP, int stride) {
    int b = blockIdx.x;
    const float* M = am + (size_t)b * N * 14;
    const float* W = ws + (size_t)b * stride;
    float s = 0.f, pairs = 0.f;
    for (int i = threadIdx.x; i < N * 14; i += blockDim.x) s += M[i];
    for (int i = threadIdx.x; i < NBP; i += blockDim.x) pairs += W[i];
    s = wave_reduce_add(s);
    pairs = wave_reduce_add(pairs);
    __shared__ float red[8];
    int lane = threadIdx.x & 63, wid = threadIdx.x >> 6;
    if (lane == 0) { red[wid] = s; red[4 + wid] = pairs; }
    __syncthreads();
    if (threadIdx.x == 0) {
        float na = fmaxf(red[0] + red[1] + red[2] + red[3], 1e-6f);
        float P2 = red[4] + red[5] + red[6] + red[7];
        const float* T6 = W + NBP;
        float loss = T6[0] / (T6[1] + EPS) + T6[2] / (T6[3] + EPS)
                   + T6[4] / (T6[5] + EPS) + 2.f * P2 / na;
        out[b] = loss;
    }
}

extern "C" void kernel_launch(void* const* d_in, const int* in_sizes, int n_in,
                              void* d_out, int out_size, void* d_ws, size_t ws_size,
                              hipStream_t stream) {
    const float* pos = (const float*)d_in[0];
    const float* am = (const float*)d_in[1];
    const int* rtypes = (const int*)d_in[2];
    const int* rindex = (const int*)d_in[3];
    const float* vdw = (const float*)d_in[4];
    const float* lbt = (const float*)d_in[5];
    const float* ubt = (const float*)d_in[6];
    float* out = (float*)d_out;
    float* ws = (float*)d_ws;

    int B = out_size;
    int N = in_sizes[2] / B;
    int A = N * 14;
    int T = (A + JT - 1) / JT;
    int CB = T * (T + 1) / 2;
    int NBP = CB + WB;          // pair-partial slots
    int stride = NBP + 6;       // + bonds tail

    dim3 grid(NBP + 1, B);
    main_kernel<<<grid, JT, 0, stream>>>(pos, am, rtypes, rindex, vdw, lbt, ubt,
                                         ws, N, A, T, CB, NBP, stride);
    final_kernel<<<B, 256, 0, stream>>>(am, ws, out, N, NBP, stride);
}

// Round 5
// 89.589 us; speedup vs baseline: 1.5966x; 1.1373x over previous
//
#include <hip/hip_runtime.h>

#define EPS 1e-6f
#define IT 512           // clash i-tile (2 per thread, 256 threads)
#define JTL 64           // clash j-tile (LDS resident)
#define RATIO 8          // IT / JTL
#define WB 64            // within-residue blocks

static __device__ __forceinline__ float wave_reduce_add(float v) {
#pragma unroll
    for (int o = 32; o > 0; o >>= 1) v += __shfl_down(v, o, 64);
    return v;
}

// ws layout per batch (stride = NBP + 6 floats):
//   [0, NBP)       per-block pair-loss partials (clash + within blocks)
//   [NBP, NBP+6)   bonds: cn_num cn_den cacn_num cacn_den cnca_num cnca_den
// Every slot written unconditionally every launch -> no zero-init needed.

__device__ void do_bonds(const float* __restrict__ P, const float* __restrict__ M,
                         const int* __restrict__ RT, const int* __restrict__ RI,
                         float* __restrict__ Wtail, int N) {
    float n0 = 0.f, de0 = 0.f, n1 = 0.f, de1 = 0.f, n2 = 0.f, de2 = 0.f;
    for (int i = threadIdx.x; i < N - 1; i += blockDim.x) {
        float no_gap = (RI[i + 1] - RI[i] == 1) ? 1.f : 0.f;
        const float* ca0 = P + i * 42 + 3;
        const float* c0  = P + i * 42 + 6;
        const float* nn  = P + (i + 1) * 42 + 0;
        const float* ca1 = P + (i + 1) * 42 + 3;
        float m_ca0 = M[i * 14 + 1], m_c0 = M[i * 14 + 2];
        float m_nn = M[(i + 1) * 14 + 0], m_ca1 = M[(i + 1) * 14 + 1];

        float bx = nn[0] - c0[0], by = nn[1] - c0[1], bz = nn[2] - c0[2];
        float c_n_len = sqrtf(bx * bx + by * by + bz * bz + EPS);
        float pro = (RT[i + 1] == 14) ? 1.f : 0.f;
        float gt_len = (1.f - pro) * 1.329f + pro * 1.341f;
        float gt_std = (1.f - pro) * 0.014f + pro * 0.016f;
        float cnm = m_c0 * m_nn * no_gap;
        float dl = c_n_len - gt_len;
        float cne = sqrtf(dl * dl + EPS);
        n0 += cnm * fmaxf(cne - 12.f * gt_std, 0.f);
        de0 += cnm;

        float ax = ca0[0] - c0[0], ay = ca0[1] - c0[1], az = ca0[2] - c0[2];
        float ca_c_len = sqrtf(ax * ax + ay * ay + az * az + EPS);
        float ex = ca1[0] - nn[0], ey = ca1[1] - nn[1], ez = ca1[2] - nn[2];
        float n_ca_len = sqrtf(ex * ex + ey * ey + ez * ez + EPS);
        float inv_cn = 1.f / c_n_len, inv_ac = 1.f / ca_c_len, inv_nc = 1.f / n_ca_len;
        float ux = bx * inv_cn, uy = by * inv_cn, uz = bz * inv_cn;
        float cx = ax * inv_ac, cy = ay * inv_ac, cz = az * inv_ac;
        float wx = ex * inv_nc, wy = ey * inv_nc, wz = ez * inv_nc;

        float cacn = cx * ux + cy * uy + cz * uz;
        float m1 = m_ca0 * m_c0 * m_nn * no_gap;
        float t1 = cacn + 0.5203f;
        float e1 = sqrtf(t1 * t1 + EPS);
        n1 += m1 * fmaxf(e1 - 12.f * 0.0353f, 0.f);
        de1 += m1;

        float cnca = -(ux * wx + uy * wy + uz * wz);
        float m2 = m_c0 * m_nn * m_ca1 * no_gap;
        float t2 = cnca + 0.4473f;
        float e2 = sqrtf(t2 * t2 + EPS);
        n2 += m2 * fmaxf(e2 - 12.f * 0.0311f, 0.f);
        de2 += m2;
    }
    n0 = wave_reduce_add(n0); de0 = wave_reduce_add(de0);
    n1 = wave_reduce_add(n1); de1 = wave_reduce_add(de1);
    n2 = wave_reduce_add(n2); de2 = wave_reduce_add(de2);
    __shared__ float red[24];
    int lane = threadIdx.x & 63, wid = threadIdx.x >> 6;
    if (lane == 0) {
        red[wid * 6 + 0] = n0; red[wid * 6 + 1] = de0; red[wid * 6 + 2] = n1;
        red[wid * 6 + 3] = de1; red[wid * 6 + 4] = n2; red[wid * 6 + 5] = de2;
    }
    __syncthreads();
    if (threadIdx.x < 6) {
        Wtail[threadIdx.x] = red[threadIdx.x] + red[6 + threadIdx.x]
                           + red[12 + threadIdx.x] + red[18 + threadIdx.x];
    }
}

__device__ void do_within(const float* __restrict__ pos, const float* __restrict__ am,
                          const int* __restrict__ rtypes,
                          const float* __restrict__ lbt, const float* __restrict__ ubt,
                          float* __restrict__ slot, int N, int b, int wblk) {
    int total = N * 196;
    float sum = 0.f;
    for (int idx = wblk * blockDim.x + threadIdx.x; idx < total; idx += WB * blockDim.x) {
        int n = idx / 196;
        int p = idx - n * 196;
        int i = p / 14;
        int j = p - i * 14;
        if (i == j) continue;
        size_t bn = (size_t)b * N + n;
        int rt = rtypes[bn]; rt = rt < 20 ? rt : 20;
        const float* pi = pos + bn * 42 + i * 3;
        const float* pj = pos + bn * 42 + j * 3;
        float dx = pi[0] - pj[0], dy = pi[1] - pj[1], dz = pi[2] - pj[2];
        float d = sqrtf(dx * dx + dy * dy + dz * dz + 1e-8f);
        float lb = lbt[rt * 196 + p], ub = ubt[rt * 196 + p];
        float gate = (lb > 0.f || ub > 0.f) ? 1.f : 0.f;
        float m = am[bn * 14 + i] * am[bn * 14 + j] * gate;
        sum += (fmaxf(lb - d, 0.f) + fmaxf(d - ub, 0.f)) * m;
    }
    sum = wave_reduce_add(sum);
    __shared__ float red2[4];
    int lane = threadIdx.x & 63, wid = threadIdx.x >> 6;
    if (lane == 0) red2[wid] = sum;
    __syncthreads();
    if (threadIdx.x == 0) *slot = red2[0] + red2[1] + red2[2] + red2[3];
}

__device__ void do_clash(const float* __restrict__ P, const float* __restrict__ M,
                         const int* __restrict__ RT, const int* __restrict__ RI,
                         const float* __restrict__ vdw, float* __restrict__ slot,
                         int N, int A, int TJ, int p) {
    // map flat p -> (bi, bj): for row bi, bj ranges over [RATIO*bi, TJ)
    int bi = 0, rem = p;
    while (true) {
        int cnt = TJ - RATIO * bi;
        cnt = cnt > 0 ? cnt : 0;
        if (rem < cnt) break;
        rem -= cnt; ++bi;
    }
    int bj = RATIO * bi + rem;

    __shared__ float4 sPos[JTL];   // x,y,z, vdw_j - 1.5
    __shared__ float sMask[JTL];
    __shared__ int sRI[JTL];
    __shared__ int sMeta[JTL];     // slot | (cys-SG << 4)

    int t = threadIdx.x;
    if (t < JTL) {
        int j = bj * JTL + t;
        if (j < A) {
            int res = j / 14;
            int sl = j - res * 14;
            int rt = RT[res];
            int rtc = rt < 20 ? rt : 20;
            sPos[t] = make_float4(P[j * 3], P[j * 3 + 1], P[j * 3 + 2],
                                  vdw[rtc * 14 + sl] - 1.5f);
            sMask[t] = M[j];
            sRI[t] = RI[res];
            sMeta[t] = sl | (((rt == 4) && (sl == 5)) ? 16 : 0);
        } else {
            sPos[t] = make_float4(1e30f, 1e30f, 1e30f, -1e30f);
            sMask[t] = 0.f; sRI[t] = 0x7fffffff; sMeta[t] = 0;
        }
    }
    __syncthreads();

    // two i atoms per thread
    int i0 = bi * IT + t;
    int i1 = i0 + 256;
    float xi0 = 0.f, yi0 = 0.f, zi0 = 0.f, vi0 = -1e30f, mi0 = 0.f;
    float xi1 = 0.f, yi1 = 0.f, zi1 = 0.f, vi1 = -1e30f, mi1 = 0.f;
    int iri0 = 0, iri1 = 0;
    bool icys0 = false, icys1 = false;
    int isl0 = -1, isl1 = -1;
    if (i0 < A) {
        int res = i0 / 14; isl0 = i0 - res * 14;
        int rt = RT[res]; int rtc = rt < 20 ? rt : 20;
        vi0 = vdw[rtc * 14 + isl0];
        xi0 = P[i0 * 3]; yi0 = P[i0 * 3 + 1]; zi0 = P[i0 * 3 + 2];
        mi0 = M[i0]; iri0 = RI[res]; icys0 = (rt == 4) && (isl0 == 5);
        if (mi0 == 0.f) vi0 = -1e30f;
    }
    if (i1 < A) {
        int res = i1 / 14; isl1 = i1 - res * 14;
        int rt = RT[res]; int rtc = rt < 20 ? rt : 20;
        vi1 = vdw[rtc * 14 + isl1];
        xi1 = P[i1 * 3]; yi1 = P[i1 * 3 + 1]; zi1 = P[i1 * 3 + 2];
        mi1 = M[i1]; iri1 = RI[res]; icys1 = (rt == 4) && (isl1 == 5);
        if (mi1 == 0.f) vi1 = -1e30f;
    }

    float sum = 0.f;
    int jbase_g = bj * JTL;
    for (int base = 0; base < JTL; base += 8) {
        float4 r[8];
#pragma unroll
        for (int k = 0; k < 8; ++k) r[k] = sPos[base + k];
#pragma unroll
        for (int k = 0; k < 8; ++k) {
            float w = r[k].w;
            // chain 0
            {
                float dx = xi0 - r[k].x, dy = yi0 - r[k].y, dz = zi0 - r[k].z;
                float d2 = dx * dx + dy * dy + dz * dz;
                float s = vi0 + w;
                if (s > 0.f && d2 < s * s) {
                    int jj = base + k, jg = jbase_g + jj;
                    if (i0 < jg) {
                        int jri = sRI[jj];
                        if (iri0 != jri) {
                            int dj = jri - iri0;
                            int jm = sMeta[jj], jsl = jm & 15;
                            bool cn = (isl0 == 2 && jsl == 0 && dj == 1) ||
                                      (isl0 == 0 && jsl == 2 && dj == -1);
                            bool ssb = icys0 && (jm & 16);
                            if (!cn && !ssb)
                                sum += (s - sqrtf(d2 + 1e-8f)) * mi0 * sMask[jj];
                        }
                    }
                }
            }
            // chain 1
            {
                float dx = xi1 - r[k].x, dy = yi1 - r[k].y, dz = zi1 - r[k].z;
                float d2 = dx * dx + dy * dy + dz * dz;
                float s = vi1 + w;
                if (s > 0.f && d2 < s * s) {
                    int jj = base + k, jg = jbase_g + jj;
                    if (i1 < jg) {
                        int jri = sRI[jj];
                        if (iri1 != jri) {
                            int dj = jri - iri1;
                            int jm = sMeta[jj], jsl = jm & 15;
                            bool cn = (isl1 == 2 && jsl == 0 && dj == 1) ||
                                      (isl1 == 0 && jsl == 2 && dj == -1);
                            bool ssb = icys1 && (jm & 16);
                            if (!cn && !ssb)
                                sum += (s - sqrtf(d2 + 1e-8f)) * mi1 * sMask[jj];
                        }
                    }
                }
            }
        }
    }
    sum = wave_reduce_add(sum);
    __shared__ float red3[4];
    int lane = t & 63, wid = t >> 6;
    if (lane == 0) red3[wid] = sum;
    __syncthreads();
    if (t == 0) *slot = red3[0] + red3[1] + red3[2] + red3[3];
}

__global__ __launch_bounds__(256, 4) void main_kernel(
        const float* __restrict__ pos, const float* __restrict__ am,
        const int* __restrict__ rtypes, const int* __restrict__ rindex,
        const float* __restrict__ vdw, const float* __restrict__ lbt,
        const float* __restrict__ ubt, float* __restrict__ ws,
        int N, int A, int TJ, int CB, int NBP, int stride) {
    int b = blockIdx.y;
    const float* P = pos + (size_t)b * A * 3;
    const float* M = am + (size_t)b * A;
    const int* RT = rtypes + (size_t)b * N;
    const int* RI = rindex + (size_t)b * N;
    float* W = ws + (size_t)b * stride;
    int bid = blockIdx.x;
    if (bid < CB) {
        do_clash(P, M, RT, RI, vdw, &W[bid], N, A, TJ, bid);
    } else if (bid < NBP) {
        do_within(pos, am, rtypes, lbt, ubt, &W[bid], N, b, bid - CB);
    } else {
        do_bonds(P, M, RT, RI, &W[NBP], N);
    }
}

__global__ __launch_bounds__(256) void final_kernel(
        const float* __restrict__ am, const float* __restrict__ ws,
        float* __restrict__ out, int N, int NBP, int stride) {
    int b = blockIdx.x;
    const float* M = am + (size_t)b * N * 14;
    const float* W = ws + (size_t)b * stride;
    float s = 0.f, pairs = 0.f;
    int A = N * 14;
    int A4 = A >> 2;
    const float4* M4 = (const float4*)M;
    for (int i = threadIdx.x; i < A4; i += blockDim.x) {
        float4 v = M4[i];
        s += v.x + v.y + v.z + v.w;
    }
    for (int i = A4 << 2; i < A; ++i) if (threadIdx.x == 0) s += M[i];
    for (int i = threadIdx.x; i < NBP; i += blockDim.x) pairs += W[i];
    s = wave_reduce_add(s);
    pairs = wave_reduce_add(pairs);
    __shared__ float red[8];
    int lane = threadIdx.x & 63, wid = threadIdx.x >> 6;
    if (lane == 0) { red[wid] = s; red[4 + wid] = pairs; }
    __syncthreads();
    if (threadIdx.x == 0) {
        float na = fmaxf(red[0] + red[1] + red[2] + red[3], 1e-6f);
        float P2 = red[4] + red[5] + red[6] + red[7];
        const float* T6 = W + NBP;
        float loss = T6[0] / (T6[1] + EPS) + T6[2] / (T6[3] + EPS)
                   + T6[4] / (T6[5] + EPS) + 2.f * P2 / na;
        out[b] = loss;
    }
}

extern "C" void kernel_launch(void* const* d_in, const int* in_sizes, int n_in,
                              void* d_out, int out_size, void* d_ws, size_t ws_size,
                              hipStream_t stream) {
    const float* pos = (const float*)d_in[0];
    const float* am = (const float*)d_in[1];
    const int* rtypes = (const int*)d_in[2];
    const int* rindex = (const int*)d_in[3];
    const float* vdw = (const float*)d_in[4];
    const float* lbt = (const float*)d_in[5];
    const float* ubt = (const float*)d_in[6];
    float* out = (float*)d_out;
    float* ws = (float*)d_ws;

    int B = out_size;
    int N = in_sizes[2] / B;
    int A = N * 14;
    int TI = (A + IT - 1) / IT;
    int TJ = (A + JTL - 1) / JTL;
    int CB = 0;
    for (int bi = 0; bi < TI; ++bi) {
        int c = TJ - RATIO * bi;
        if (c > 0) CB += c;
    }
    int NBP = CB + WB;          // pair-partial slots
    int stride = NBP + 6;       // + bonds tail

    dim3 grid(NBP + 1, B);
    main_kernel<<<grid, 256, 0, stream>>>(pos, am, rtypes, rindex, vdw, lbt, ubt,
                                          ws, N, A, TJ, CB, NBP, stride);
    final_kernel<<<B, 256, 0, stream>>>(am, ws, out, N, NBP, stride);
}